// Round 1
// baseline (386.490 us; speedup 1.0000x reference)
//
#include <hip/hip_runtime.h>
#include <hip/hip_bf16.h>

typedef _Float16 half8 __attribute__((ext_vector_type(8)));
typedef _Float16 half4 __attribute__((ext_vector_type(4)));
typedef float f32x4 __attribute__((ext_vector_type(4)));

#define DIM 512
#define MEMSZ 1024
#define NPIX 4096
#define NT 64

// Swizzle: spreads across 8 16B slots for BOTH the read pattern (n varies 0..15
// consecutively at fixed k) and the staging-write pattern.
#define SWZ(n) ((((n) ^ ((n) >> 3)) & 7) << 4)

// prep: memory fp32 [512][1024] -> mem_h fp16 [512][1024] and memT_h fp16 [1024][512]
__global__ void prep_kernel(const float* __restrict__ mem, _Float16* __restrict__ mem_h,
                            _Float16* __restrict__ memT_h) {
    int idx = blockIdx.x * 256 + threadIdx.x;   // 0 .. 512*1024-1
    int c = idx >> 10, m = idx & 1023;
    float v = mem[idx];
    _Float16 h = (_Float16)v;
    mem_h[idx] = h;
    memT_h[m * DIM + c] = h;
}

// 16 waves (4/SIMD) -- occupancy doubled vs the 8-wave r6 kernel. Per-wave tiles
// halved so total regs (VGPR+AGPR unified on gfx950) stay <=128/wave:
//   GEMM1: wave owns 64 m x 64 n  -> acc1[4][4] = 64 regs
//   GEMM2: wave owns 32 c x 64 n  -> acc2[2][4] = 32 regs
// A-fragments (global/L2, ~220cyc) double-buffered; B-fragments (LDS) single-
// buffered -- at 4 waves/SIMD the LDS latency is covered by TLP.
__global__ __launch_bounds__(1024)
void fused_kernel(const float* __restrict__ x, const _Float16* __restrict__ mem_h,
                  const _Float16* __restrict__ memT_h, float* __restrict__ out) {
    // LDS: [0,64K)  = xT fp16 [64 n][512 c], row stride 1024B, swizzled  (GEMM1)
    //      [0,128K) = pT fp16 [64 n][1024 m], row stride 2048B, swizzled (GEMM2)
    //      [128K,+4K) = red1 (max, [64 n][16 w]), [+4K,+8K) = red2 (sum)
    __shared__ char smem[131072 + 8192];
    float* red1 = (float*)(smem + 131072);
    float* red2 = (float*)(smem + 135168);

    const int tid  = threadIdx.x;
    const int lane = tid & 63;
    const int w    = tid >> 6;               // wave 0..15
    const int bidx = blockIdx.x;
    const int b    = bidx >> 6;              // batch
    const int n0   = (bidx & 63) * NT;       // column tile start

    // ---- stage x tile -> xT LDS (fp32 -> fp16, 4x4 micro-transpose, swizzled) ----
    {
        const int nq = (tid & 15) * 4;       // n quad base 0..60
        const int cq = (tid >> 4) * 4;       // c quad base 0..252
        const float* xp = x + (size_t)b * DIM * NPIX + n0 + nq;
        f32x4 v[8];
        #pragma unroll
        for (int it = 0; it < 2; ++it)
            #pragma unroll
            for (int r = 0; r < 4; ++r)
                v[it * 4 + r] = __builtin_nontemporal_load(
                    (const f32x4*)(xp + (size_t)(cq + it * 256 + r) * NPIX));
        #pragma unroll
        for (int it = 0; it < 2; ++it) {
            int c = cq + it * 256;
            #pragma unroll
            for (int i = 0; i < 4; ++i) {
                int n = nq + i;
                half4 h = { (_Float16)v[it * 4 + 0][i], (_Float16)v[it * 4 + 1][i],
                            (_Float16)v[it * 4 + 2][i], (_Float16)v[it * 4 + 3][i] };
                int byte = (n * 1024 + c * 2) ^ SWZ(n);
                *(half4*)(smem + byte) = h;
            }
        }
    }
    __syncthreads();

    const int kg = (lane >> 4) * 8;

    // ---- GEMM1: logits[m][n], wave w owns m in [w*64, w*64+64), n all 64 ----
    f32x4 acc1[4][4];
    #pragma unroll
    for (int mi = 0; mi < 4; ++mi)
        #pragma unroll
        for (int ni = 0; ni < 4; ++ni)
            acc1[mi][ni] = (f32x4){0.f, 0.f, 0.f, 0.f};

    {
        const _Float16* aptr = memT_h + (size_t)(w * 64 + (lane & 15)) * DIM + kg;
        half8 aC[4], aN[4], bC[4];

        #define LD_A1(dst, k0)                                                     \
            _Pragma("unroll")                                                      \
            for (int mi = 0; mi < 4; ++mi)                                         \
                dst[mi] = *(const half8*)(aptr + (size_t)mi * 16 * DIM + (k0));
        #define LD_B1(dst, k0)                                                     \
            _Pragma("unroll")                                                      \
            for (int ni = 0; ni < 4; ++ni) {                                       \
                int n = ni * 16 + (lane & 15);                                     \
                int byte = (n * 1024 + ((k0) + kg) * 2) ^ SWZ(n);                  \
                dst[ni] = *(const half8*)(smem + byte);                            \
            }
        #define MFMA1(a, bfr)                                                      \
            __builtin_amdgcn_s_setprio(1);                                         \
            _Pragma("unroll")                                                      \
            for (int mi = 0; mi < 4; ++mi)                                         \
                _Pragma("unroll")                                                  \
                for (int ni = 0; ni < 4; ++ni)                                     \
                    acc1[mi][ni] = __builtin_amdgcn_mfma_f32_16x16x32_f16(         \
                        a[mi], bfr[ni], acc1[mi][ni], 0, 0, 0);                    \
            __builtin_amdgcn_s_setprio(0);

        LD_A1(aC, 0)
        for (int k0 = 0; k0 < DIM; k0 += 64) {
            LD_A1(aN, k0 + 32)       // next-half A issued BEFORE current MFMAs
            LD_B1(bC, k0)
            MFMA1(aC, bC)
            LD_A1(aC, (k0 + 64) & (DIM - 1))
            LD_B1(bC, k0 + 32)       // bC reuse: reads issued after consuming MFMAs
            MFMA1(aN, bC)
        }
        #undef LD_A1
        #undef LD_B1
        #undef MFMA1
    }

    // ---- softmax over m (distributed across 16 waves), 2 barriers ----
    // C/D layout: col = lane&15 (n), row = (lane>>4)*4 + r (m within 16)
    float gsum[4];
    {
        float gmax[4], pm[4];
        #pragma unroll
        for (int ni = 0; ni < 4; ++ni) {
            float m0 = -1e30f;
            #pragma unroll
            for (int mi = 0; mi < 4; ++mi)
                #pragma unroll
                for (int r = 0; r < 4; ++r) m0 = fmaxf(m0, acc1[mi][ni][r]);
            m0 = fmaxf(m0, __shfl_xor(m0, 16));
            m0 = fmaxf(m0, __shfl_xor(m0, 32));
            pm[ni] = m0;
        }
        if (lane < 16) {
            #pragma unroll
            for (int ni = 0; ni < 4; ++ni) red1[(ni * 16 + lane) * 16 + w] = pm[ni];
        }
        __syncthreads();
        #pragma unroll
        for (int ni = 0; ni < 4; ++ni) {
            const f32x4* rv = (const f32x4*)&red1[(ni * 16 + (lane & 15)) * 16];
            float m0 = -1e30f;
            #pragma unroll
            for (int jq = 0; jq < 4; ++jq) {
                f32x4 vv = rv[jq];
                m0 = fmaxf(m0, fmaxf(fmaxf(vv[0], vv[1]), fmaxf(vv[2], vv[3])));
            }
            gmax[ni] = m0;
        }

        float ps[4];
        #pragma unroll
        for (int ni = 0; ni < 4; ++ni) {
            float s = 0.f;
            #pragma unroll
            for (int mi = 0; mi < 4; ++mi)
                #pragma unroll
                for (int r = 0; r < 4; ++r) {
                    float e = __expf(acc1[mi][ni][r] - gmax[ni]);
                    acc1[mi][ni][r] = e;     // keep unnormalized p in regs
                    s += e;
                }
            s += __shfl_xor(s, 16);
            s += __shfl_xor(s, 32);
            ps[ni] = s;
        }
        if (lane < 16) {
            #pragma unroll
            for (int ni = 0; ni < 4; ++ni) red2[(ni * 16 + lane) * 16 + w] = ps[ni];
        }
        __syncthreads();
        #pragma unroll
        for (int ni = 0; ni < 4; ++ni) {
            const f32x4* rv = (const f32x4*)&red2[(ni * 16 + (lane & 15)) * 16];
            float s = 0.f;
            #pragma unroll
            for (int jq = 0; jq < 4; ++jq) {
                f32x4 vv = rv[jq];
                s += (vv[0] + vv[1]) + (vv[2] + vv[3]);
            }
            gsum[ni] = s;   // lane's n-col mapping identical in GEMM2 epilogue
        }
        // no barrier needed: pT region [0,128K) disjoint from red1/red2, and all
        // xT reads completed before the first softmax barrier.
    }

    // ---- write unnormalized p (fp16) to pT LDS [n][m], swizzled ----
    #pragma unroll
    for (int ni = 0; ni < 4; ++ni) {
        int n = ni * 16 + (lane & 15);
        #pragma unroll
        for (int mi = 0; mi < 4; ++mi) {
            int m = w * 64 + mi * 16 + (lane >> 4) * 4;
            half4 h;
            #pragma unroll
            for (int r = 0; r < 4; ++r) h[r] = (_Float16)acc1[mi][ni][r];
            int byte = (n * 2048 + m * 2) ^ SWZ(n);
            *(half4*)(smem + byte) = h;
        }
    }
    __syncthreads();

    // ---- GEMM2: out[c][n] = sum_m mem[c][m] * p[m][n]; wave w owns c in [w*32, w*32+32) ----
    f32x4 acc2[2][4];
    #pragma unroll
    for (int ci = 0; ci < 2; ++ci)
        #pragma unroll
        for (int ni = 0; ni < 4; ++ni)
            acc2[ci][ni] = (f32x4){0.f, 0.f, 0.f, 0.f};

    {
        const _Float16* aptr = mem_h + (size_t)(w * 32 + (lane & 15)) * MEMSZ + kg;
        half8 aC[2], aN[2], bC[4];

        #define LD_A2(dst, k0)                                                     \
            _Pragma("unroll")                                                      \
            for (int ci = 0; ci < 2; ++ci)                                         \
                dst[ci] = *(const half8*)(aptr + (size_t)ci * 16 * MEMSZ + (k0));
        #define LD_B2(dst, k0)                                                     \
            _Pragma("unroll")                                                      \
            for (int ni = 0; ni < 4; ++ni) {                                       \
                int n = ni * 16 + (lane & 15);                                     \
                int byte = (n * 2048 + ((k0) + kg) * 2) ^ SWZ(n);                  \
                dst[ni] = *(const half8*)(smem + byte);                            \
            }
        #define MFMA2(a, bfr)                                                      \
            __builtin_amdgcn_s_setprio(1);                                         \
            _Pragma("unroll")                                                      \
            for (int ci = 0; ci < 2; ++ci)                                         \
                _Pragma("unroll")                                                  \
                for (int ni = 0; ni < 4; ++ni)                                     \
                    acc2[ci][ni] = __builtin_amdgcn_mfma_f32_16x16x32_f16(         \
                        a[ci], bfr[ni], acc2[ci][ni], 0, 0, 0);                    \
            __builtin_amdgcn_s_setprio(0);

        LD_A2(aC, 0)
        for (int k0 = 0; k0 < MEMSZ; k0 += 64) {
            LD_A2(aN, k0 + 32)
            LD_B2(bC, k0)
            MFMA2(aC, bC)
            LD_A2(aC, (k0 + 64) & (MEMSZ - 1))
            LD_B2(bC, k0 + 32)
            MFMA2(aN, bC)
        }
        #undef LD_A2
        #undef LD_B2
        #undef MFMA2
    }

    // ---- epilogue: normalize by 1/gsum and store (non-temporal) ----
    {
        float rinv[4];
        #pragma unroll
        for (int ni = 0; ni < 4; ++ni) rinv[ni] = 1.f / gsum[ni];
        #pragma unroll
        for (int ci = 0; ci < 2; ++ci) {
            #pragma unroll
            for (int ni = 0; ni < 4; ++ni) {
                int c = w * 32 + ci * 16 + (lane >> 4) * 4;
                int n = n0 + ni * 16 + (lane & 15);
                float* op = out + (size_t)(b * DIM + c) * NPIX + n;
                #pragma unroll
                for (int r = 0; r < 4; ++r)
                    __builtin_nontemporal_store(acc2[ci][ni][r] * rinv[ni],
                                                op + (size_t)r * NPIX);
            }
        }
    }
}

extern "C" void kernel_launch(void* const* d_in, const int* in_sizes, int n_in,
                              void* d_out, int out_size, void* d_ws, size_t ws_size,
                              hipStream_t stream) {
    const float* x   = (const float*)d_in[0];
    const float* mem = (const float*)d_in[1];
    float* out = (float*)d_out;

    _Float16* mem_h  = (_Float16*)d_ws;                  // [512][1024] fp16, 1 MB
    _Float16* memT_h = mem_h + (size_t)DIM * MEMSZ;      // [1024][512] fp16, 1 MB

    prep_kernel<<<2048, 256, 0, stream>>>(mem, mem_h, memT_h);
    fused_kernel<<<16 * 64, 1024, 0, stream>>>(x, mem_h, memT_h, out);
}